// Round 10
// baseline (39.529 us; speedup 1.0000x reference)
//
#include <hip/hip_runtime.h>

typedef _Float16 half2_t __attribute__((ext_vector_type(2)));
typedef _Float16 f16x8 __attribute__((ext_vector_type(8)));
typedef float f32x4 __attribute__((ext_vector_type(4)));

#define DEC 256
#define TFULL 4096
#define WIN0 3584               // x window start (t0min-128 = 3712 >= 3584)
#define WLAYER_U32 11264        // preA 1024 + f 4096 + g 4096 + p 2048
#define WTOT_U32 (8 * WLAYER_U32)          // 90112
#define X16_U32 (32 * 512 * 16)            // 262144, x16t[b][tw512][cp16]
#define XP_U32 (WTOT_U32 + X16_U32)        // 352256
#define WS_NEED ((size_t)XP_U32 * 4)

// fused-kernel LDS map (u32 indices), 2560 u32 = 10240 B:
//   h   [0,576):      row c(16), stride 36, 32 u32 of o-pairs
//   s   [576,864):    row tt(8), stride 36
//   exch/accf f32 [1536,2112): [o64] stride 9
//   head: zbuf f32 [0,1024) overlays h+s; red f32 [1024,1088)
#define EXCH_U32 1536
#define LDS1_U32 2560

__device__ __forceinline__ float fast_tanh(float x) {
    float xa = fminf(fmaxf(x, -10.f), 10.f);
    float e = __expf(2.f * xa);
    return (e - 1.f) * __builtin_amdgcn_rcpf(e + 1.f);
}
__device__ __forceinline__ unsigned pk_rte(float a, float b) {
    union { _Float16 h[2]; unsigned u; } v;
    v.h[0] = (_Float16)a; v.h[1] = (_Float16)b; return v.u;
}
__device__ __forceinline__ half2_t h2(unsigned u) {
    return __builtin_bit_cast(half2_t, u);
}
__device__ __forceinline__ unsigned pkrtz(float a, float b) {
    return __builtin_bit_cast(unsigned, __builtin_amdgcn_cvt_pkrtz(a, b));
}

// ---------------- prep: pack weights + x window to f16 (R9 layout) ----------
__global__ __launch_bounds__(512) void wavenet_prep16(
    const float* __restrict__ x,
    const float* __restrict__ pre_w,
    const float* __restrict__ fw, const float* __restrict__ gw,
    const float* __restrict__ pw, unsigned* __restrict__ ws)
{
    int idx = blockIdx.x * 512 + threadIdx.x;
    if (idx >= XP_U32) return;
    unsigned v;
    if (idx < WTOT_U32) {
        int i = idx / WLAYER_U32;
        int r = idx - i * WLAYER_U32;
        if (r < 1024) {
            int kg = r >> 8, o = (r >> 2) & 63, e = r & 3;
            const float* p = pre_w + (i * 64 + o) * 32 + 8 * kg + 2 * e;
            v = pk_rte(p[0], p[1]);
        } else if (r < 9216) {
            const int isg = (r >= 5120);
            int e2 = r - (isg ? 5120 : 1024);
            int kb = e2 >> 8, o = (e2 >> 2) & 63, e = e2 & 3;
            int m = kb >> 2, h4g = kb & 3;
            int tap = m >> 1;
            int c = 32 * (m & 1) + 8 * h4g + 2 * e;
            const float* src = isg ? gw : fw;
            const float* p = src + ((i * 64 + o) * 64 + c) * 2 + tap;
            v = pk_rte(p[0], p[2]);   // (w[o][c][tap], w[o][c+1][tap])
        } else {
            int e3 = r - 9216;
            int kg = e3 >> 8, o = (e3 >> 2) & 63, e = e3 & 3;
            const float* p = pw + (i * 64 + o) * 64 + 8 * kg + 2 * e;
            v = pk_rte(p[0], p[1]);
        }
    } else {
        int e = idx - WTOT_U32;
        int b = e >> 13, r2 = e & 8191;
        int tw = r2 >> 4, cp = r2 & 15;
        const float* p = x + (size_t)(b * 32 + 2 * cp) * TFULL + WIN0 + tw;
        v = pk_rte(p[0], p[TFULL]);
    }
    ws[idx] = v;
}

// ---------------- fused single kernel: all layers + head per 8-col tile ----
// grid 1024 = b(32) x tq(32); 512 threads (8 waves); LDS 10240 B.
// Per layer: P1(waves 0-3, 1 MFMA) -> barA -> P2(wave: o-tile wv>>1,
// F/G = wv&1, 4 MFMA full-K) -> barB(g publish) -> s -> barC ->
// P3(wave: o-tile wv>>1, K-half wv&1, 1 MFMA) -> barD(reduce) -> acc (odd waves).
__global__ __launch_bounds__(512) void wavenet_one(
    const unsigned* __restrict__ wsu,
    const float* __restrict__ pre_b,
    const float* __restrict__ filt_b, const float* __restrict__ gate_b,
    const float* __restrict__ post_b,
    const float* __restrict__ d1_w, const float* __restrict__ d1_b,
    const float* __restrict__ d2_w, const float* __restrict__ d2_b,
    float* __restrict__ out)
{
    __shared__ __align__(16) unsigned lds[LDS1_U32];
    float* exch = (float*)(lds + EXCH_U32);   // [o64] stride 9 f32

    const int tid = threadIdx.x;
    const int b = blockIdx.x >> 5;
    const int tq = blockIdx.x & 31;
    const int t0 = TFULL - DEC + tq * 8;

    const int lane = tid & 63;
    const int wv = __builtin_amdgcn_readfirstlane(tid >> 6); // 0..7
    const int h4 = lane >> 4;       // 0..3 (k-group)
    const int ln = lane & 15;
    const int tt = ln & 7;          // output col within tile (lanes 8-15 dup)

    const unsigned* xw = wsu + WTOT_U32 + b * 8192;

    const int mt = wv >> 1;         // o-tile for P2/P3
    const int fg = wv & 1;          // P2: 0=F 1=G; P3: K-half

    float acc[4] = {0.f, 0.f, 0.f, 0.f};  // skip acc: odd waves, lanes ln<8

    for (int i = 0; i < 8; ++i) {
        const int dil = 1 << i;
        const unsigned* wl = wsu + i * WLAYER_U32;

        // ---- P1 (waves 0-3): h[o64][c16], c: lo seg t0-dil+.., hi seg t0+.. ----
        if (wv < 4) {
            const int m1 = wv;
            f16x8 a = *(const f16x8*)(wl + (h4 * 64 + m1 * 16 + ln) * 4);
            float4 pb4 = *(const float4*)(pre_b + i * 64 + m1 * 16 + 4 * h4);
            const int ta = (ln < 8) ? (t0 - dil + ln) : (t0 + ln - 8);
            const int tw = ta - WIN0;      // always in [128, 512)
            f16x8 bx = *(const f16x8*)(xw + tw * 16 + h4 * 4);
            f32x4 c = {0.f, 0.f, 0.f, 0.f};
            c = __builtin_amdgcn_mfma_f32_16x16x32_f16(a, bx, c, 0, 0, 0);
            // D: row o = m1*16 + 4*h4 + reg, col c = ln
            uint2 hv;
            hv.x = pkrtz(fmaxf(c[0] + pb4.x, 0.f), fmaxf(c[1] + pb4.y, 0.f));
            hv.y = pkrtz(fmaxf(c[2] + pb4.z, 0.f), fmaxf(c[3] + pb4.w, 0.f));
            *(uint2*)&lds[ln * 36 + m1 * 8 + h4 * 2] = hv;
        }
        __syncthreads();   // barA: h ready

        // ---- P2: F or G, o-tile mt, full K=128 (tap0 rows tt, tap1 rows 8+tt) ----
        f32x4 cv = {0.f, 0.f, 0.f, 0.f};
        {
            const unsigned* wA = wl + (fg ? 5120 : 1024);
#pragma unroll
            for (int m = 0; m < 4; ++m) {
                const int kbg = 4 * m + h4;
                const int row = (m >> 1) ? (8 + tt) : tt;
                uint4 bf4 = *(const uint4*)&lds[row * 36 + 16 * (m & 1) + 4 * h4];
                f16x8 bfrag = __builtin_bit_cast(f16x8, bf4);
                f16x8 af = *(const f16x8*)(wA + (kbg * 64 + mt * 16 + ln) * 4);
                cv = __builtin_amdgcn_mfma_f32_16x16x32_f16(af, bfrag, cv, 0, 0, 0);
            }
        }
        if (fg && ln < 8) {           // G publishes
#pragma unroll
            for (int r = 0; r < 4; ++r)
                exch[(mt * 16 + 4 * h4 + r) * 9 + tt] = cv[r];
        }
        __syncthreads();   // barB
        if (!fg && ln < 8) {          // F computes s, writes packed f16
            float4 fb = *(const float4*)(filt_b + i * 64 + mt * 16 + 4 * h4);
            float4 gb = *(const float4*)(gate_b + i * 64 + mt * 16 + 4 * h4);
            const int o0 = mt * 16 + 4 * h4;
            float g0 = exch[(o0 + 0) * 9 + tt] + gb.x;
            float g1 = exch[(o0 + 1) * 9 + tt] + gb.y;
            float g2 = exch[(o0 + 2) * 9 + tt] + gb.z;
            float g3 = exch[(o0 + 3) * 9 + tt] + gb.w;
            float s0 = fast_tanh(cv[0] + fb.x) * fmaxf(g0, 0.f);
            float s1 = fast_tanh(cv[1] + fb.y) * fmaxf(g1, 0.f);
            float s2 = fast_tanh(cv[2] + fb.z) * fmaxf(g2, 0.f);
            float s3 = fast_tanh(cv[3] + fb.w) * fmaxf(g3, 0.f);
            uint2 sv;
            sv.x = pkrtz(s0, s1);
            sv.y = pkrtz(s2, s3);
            *(uint2*)&lds[576 + tt * 36 + mt * 8 + h4 * 2] = sv;
        }
        __syncthreads();   // barC: s ready

        // ---- P3: o-tile mt, K-half fg (kg = 4*fg + h4), 1 MFMA ----
        {
            const int kg = 4 * fg + h4;
            uint4 bs4 = *(const uint4*)&lds[576 + tt * 36 + 4 * kg];
            f16x8 bs = __builtin_bit_cast(f16x8, bs4);
            f16x8 ap = *(const f16x8*)(wl + 9216 + (kg * 64 + mt * 16 + ln) * 4);
            f32x4 cp = {0.f, 0.f, 0.f, 0.f};
            cp = __builtin_amdgcn_mfma_f32_16x16x32_f16(ap, bs, cp, 0, 0, 0);
            if (!fg && ln < 8) {      // K-half 0 publishes
#pragma unroll
                for (int r = 0; r < 4; ++r)
                    exch[(mt * 16 + 4 * h4 + r) * 9 + tt] = cp[r];
            }
            __syncthreads();  // barD
            if (fg) {                 // K-half 1 reduces + accumulates skip
                float4 pb = *(const float4*)(post_b + i * 64 + mt * 16 + 4 * h4);
                const int o0 = mt * 16 + 4 * h4;
                acc[0] += fmaxf(cp[0] + exch[(o0 + 0) * 9 + tt] + pb.x, 0.f);
                acc[1] += fmaxf(cp[1] + exch[(o0 + 1) * 9 + tt] + pb.y, 0.f);
                acc[2] += fmaxf(cp[2] + exch[(o0 + 2) * 9 + tt] + pb.z, 0.f);
                acc[3] += fmaxf(cp[3] + exch[(o0 + 3) * 9 + tt] + pb.w, 0.f);
            }
        }
        // next P1 writes h (disjoint from s/exch); h readers finished pre-barB
    }

    // ---- acc -> accf (exch region, same rows each odd wave read) ----
    if (fg && ln < 8) {
#pragma unroll
        for (int r = 0; r < 4; ++r)
            exch[(mt * 16 + 4 * h4 + r) * 9 + tt] = acc[r];
    }
    __syncthreads();

    // ---- head: dense 64 -> 128 -> 1 for 8 cols ----
    float* zbuf = (float*)lds;              // [128][8] f32, overlays h+s
    float* red = (float*)(lds + 1024);      // [8][8]
    {
#pragma unroll
        for (int k = 0; k < 2; ++k) {
            const int j = tid + 512 * k;    // 1024 jobs: p = j>>3, col = j&7
            const int p = j >> 3, tc = j & 7;
            float z = d1_b[p];
            const float4* w4 = (const float4*)(d1_w + p * 64);
#pragma unroll 4
            for (int c4 = 0; c4 < 16; ++c4) {
                float4 w = w4[c4];
                z = fmaf(w.x, exch[(c4 * 4 + 0) * 9 + tc], z);
                z = fmaf(w.y, exch[(c4 * 4 + 1) * 9 + tc], z);
                z = fmaf(w.z, exch[(c4 * 4 + 2) * 9 + tc], z);
                z = fmaf(w.w, exch[(c4 * 4 + 3) * 9 + tc], z);
            }
            zbuf[p * 8 + tc] = fmaxf(z, 0.f) * d2_w[p];
        }
    }
    __syncthreads();
    if (tid < 64) {
        const int tc = tid & 7, seg = tid >> 3;
        float sum = 0.f;
#pragma unroll
        for (int k = 0; k < 16; ++k)
            sum += zbuf[(seg * 16 + k) * 8 + tc];
        red[tc * 8 + seg] = sum;
    }
    __syncthreads();
    if (tid < 8) {
        float sum = d2_b[0];
#pragma unroll
        for (int g = 0; g < 8; ++g) sum += red[tid * 8 + g];
        out[b * DEC + tq * 8 + tid] = fmaxf(sum, 0.f);
    }
}

// ================= fallback: fp32 fused (no ws) =================
#define HROW 164
#define SROW 33
__global__ __launch_bounds__(512) void wavenet_main(
    const float* __restrict__ x,
    const float* __restrict__ pre_w, const float* __restrict__ pre_b,
    const float* __restrict__ filt_w, const float* __restrict__ filt_b,
    const float* __restrict__ gate_w, const float* __restrict__ gate_b,
    const float* __restrict__ post_w, const float* __restrict__ post_b,
    const float* __restrict__ d1_w, const float* __restrict__ d1_b,
    const float* __restrict__ d2_w, const float* __restrict__ d2_b,
    float* __restrict__ out)
{
    __shared__ __align__(16) float h_s[64 * HROW];
    __shared__ __align__(16) float wbuf[20480];
    __shared__ __align__(16) float s_s[64 * SROW];
    const int tid = threadIdx.x;
    const int b = blockIdx.x >> 3;
    const int tile = blockIdx.x & 7;
    const int t0 = TFULL - DEC + tile * 32;
    const int lane = tid & 63;
    const int wv = __builtin_amdgcn_readfirstlane(tid >> 6);
    const int q = tid >> 5;
    const int tt = tid & 31;
    float accp[4] = {0.f, 0.f, 0.f, 0.f};
    for (int i = 0; i < 8; ++i) {
        const int dil = 1 << i;
        const int NC = 32 + dil;
        for (int m = tid; m < 8192; m += 512) {
            int c = m >> 7, rem = m & 127, o = rem >> 1, k = m & 1;
            wbuf[m] = filt_w[((i * 64 + o) * 64 + c) * 2 + k];
            wbuf[8192 + m] = gate_w[((i * 64 + o) * 64 + c) * 2 + k];
        }
        for (int m = tid; m < 4096; m += 512) {
            int c = m >> 6, o = m & 63;
            wbuf[16384 + m] = post_w[(i * 64 + o) * 64 + c];
        }
        __syncthreads();
        {
            const float* preb = pre_b + i * 64 + wv * 8;
            const float* prew = pre_w + (i * 64 + wv * 8) * 32;
            for (int col = lane; col < NC; col += 64) {
                int ta = t0 - dil + col;
                const float* xp = x + (size_t)b * 32 * TFULL + ta;
                float hacc[8];
#pragma unroll
                for (int r = 0; r < 8; ++r) hacc[r] = preb[r];
                for (int ci = 0; ci < 32; ++ci) {
                    float xv = xp[ci * TFULL];
#pragma unroll
                    for (int r = 0; r < 8; ++r)
                        hacc[r] = fmaf(prew[r * 32 + ci], xv, hacc[r]);
                }
#pragma unroll
                for (int r = 0; r < 8; ++r)
                    h_s[(wv * 8 + r) * HROW + col] = fmaxf(hacc[r], 0.f);
            }
        }
        __syncthreads();
        {
            float fa[4], ga[4];
#pragma unroll
            for (int oo = 0; oo < 4; ++oo) {
                fa[oo] = filt_b[i * 64 + q * 4 + oo];
                ga[oo] = gate_b[i * 64 + q * 4 + oo];
            }
            const float4* fw4 = (const float4*)wbuf;
            const float4* gw4 = (const float4*)(wbuf + 8192);
            const float* hrow0 = h_s + tt;
            const float* hrow1 = h_s + tt + dil;
#pragma unroll 4
            for (int c = 0; c < 64; ++c) {
                float4 f0 = fw4[c * 32 + q * 2];
                float4 f1 = fw4[c * 32 + q * 2 + 1];
                float4 g0 = gw4[c * 32 + q * 2];
                float4 g1 = gw4[c * 32 + q * 2 + 1];
                float h0 = hrow0[c * HROW];
                float h1 = hrow1[c * HROW];
                fa[0] = fmaf(f0.x, h0, fmaf(f0.y, h1, fa[0]));
                fa[1] = fmaf(f0.z, h0, fmaf(f0.w, h1, fa[1]));
                fa[2] = fmaf(f1.x, h0, fmaf(f1.y, h1, fa[2]));
                fa[3] = fmaf(f1.z, h0, fmaf(f1.w, h1, fa[3]));
                ga[0] = fmaf(g0.x, h0, fmaf(g0.y, h1, ga[0]));
                ga[1] = fmaf(g0.z, h0, fmaf(g0.w, h1, ga[1]));
                ga[2] = fmaf(g1.x, h0, fmaf(g1.y, h1, ga[2]));
                ga[3] = fmaf(g1.z, h0, fmaf(g1.w, h1, ga[3]));
            }
#pragma unroll
            for (int oo = 0; oo < 4; ++oo)
                s_s[(q * 4 + oo) * SROW + tt] = fast_tanh(fa[oo]) * fmaxf(ga[oo], 0.f);
        }
        __syncthreads();
        {
            float pa[4];
#pragma unroll
            for (int oo = 0; oo < 4; ++oo) pa[oo] = post_b[i * 64 + q * 4 + oo];
            const float4* pw4 = (const float4*)(wbuf + 16384);
#pragma unroll 4
            for (int c = 0; c < 64; ++c) {
                float4 pv = pw4[c * 16 + q];
                float sv = s_s[c * SROW + tt];
                pa[0] = fmaf(pv.x, sv, pa[0]);
                pa[1] = fmaf(pv.y, sv, pa[1]);
                pa[2] = fmaf(pv.z, sv, pa[2]);
                pa[3] = fmaf(pv.w, sv, pa[3]);
            }
#pragma unroll
            for (int oo = 0; oo < 4; ++oo) accp[oo] += fmaxf(pa[oo], 0.f);
        }
        __syncthreads();
    }
#pragma unroll
    for (int oo = 0; oo < 4; ++oo) s_s[(q * 4 + oo) * SROW + tt] = accp[oo];
    __syncthreads();
    {
        const int pg = tid >> 5;
        float partial = 0.f;
#pragma unroll
        for (int pp = 0; pp < 8; ++pp) {
            const int p = pg * 8 + pp;
            float z = d1_b[p];
            const float4* w4 = (const float4*)(d1_w + p * 64);
#pragma unroll 4
            for (int c4 = 0; c4 < 16; ++c4) {
                float4 w = w4[c4];
                z = fmaf(w.x, s_s[(c4 * 4 + 0) * SROW + tt], z);
                z = fmaf(w.y, s_s[(c4 * 4 + 1) * SROW + tt], z);
                z = fmaf(w.z, s_s[(c4 * 4 + 2) * SROW + tt], z);
                z = fmaf(w.w, s_s[(c4 * 4 + 3) * SROW + tt], z);
            }
            partial = fmaf(d2_w[p], fmaxf(z, 0.f), partial);
        }
        h_s[pg * 32 + tt] = partial;
    }
    __syncthreads();
    if (tid < 32) {
        float sum = d2_b[0];
#pragma unroll
        for (int g = 0; g < 16; ++g) sum += h_s[g * 32 + tid];
        out[b * DEC + tile * 32 + tid] = fmaxf(sum, 0.f);
    }
}

extern "C" void kernel_launch(void* const* d_in, const int* in_sizes, int n_in,
                              void* d_out, int out_size, void* d_ws, size_t ws_size,
                              hipStream_t stream)
{
    const float* x      = (const float*)d_in[0];
    const float* pre_w  = (const float*)d_in[1];
    const float* pre_b  = (const float*)d_in[2];
    const float* filt_w = (const float*)d_in[3];
    const float* filt_b = (const float*)d_in[4];
    const float* gate_w = (const float*)d_in[5];
    const float* gate_b = (const float*)d_in[6];
    const float* post_w = (const float*)d_in[7];
    const float* post_b = (const float*)d_in[8];
    const float* d1_w   = (const float*)d_in[9];
    const float* d1_b   = (const float*)d_in[10];
    const float* d2_w   = (const float*)d_in[11];
    const float* d2_b   = (const float*)d_in[12];
    float* out = (float*)d_out;

    if (ws_size >= WS_NEED) {
        unsigned* ws = (unsigned*)d_ws;
        wavenet_prep16<<<688, 512, 0, stream>>>(x, pre_w, filt_w, gate_w, post_w, ws);
        wavenet_one<<<1024, 512, 0, stream>>>(
            ws, pre_b, filt_b, gate_b, post_b, d1_w, d1_b, d2_w, d2_b, out);
    } else {
        wavenet_main<<<256, 512, 0, stream>>>(
            x, pre_w, pre_b, filt_w, filt_b, gate_w, gate_b, post_w, post_b,
            d1_w, d1_b, d2_w, d2_b, out);
    }
}

// Round 11
// 27.747 us; speedup vs baseline: 1.4246x; 1.4246x over previous
//
#include <hip/hip_runtime.h>

typedef _Float16 half2_t __attribute__((ext_vector_type(2)));
typedef _Float16 f16x8 __attribute__((ext_vector_type(8)));
typedef float f32x4 __attribute__((ext_vector_type(4)));

#define DEC 256
#define TFULL 4096
#define WIN0 3584               // x window start (t0min-128 = 3712 >= 3584)
#define WLAYER_U32 11264        // preA 1024 + f 4096 + g 4096 + p 2048
#define WTOT_U32 (8 * WLAYER_U32)          // 90112
#define X16_U32 (32 * 512 * 16)            // 262144, x16t[b][tw512][cp16]
#define P_U32 (8 * 256 * 1024)             // skip partials, f16x2 packed
#define XP_U32 (WTOT_U32 + X16_U32)        // 352256
#define WS_NEED2 ((size_t)(XP_U32 + P_U32) * 4)

#define HSTR 36                 // h LDS row stride (u32), mult of 4 for b128
#define SSTR 36                 // s LDS row stride (u32)
#define HU (64 * HSTR)          // 2304 u32
#define LDS_U32 (HU + 32 * SSTR)  // 3456 u32 = 13824 B

__device__ __forceinline__ float fast_tanh(float x) {
    float xa = fminf(fmaxf(x, -10.f), 10.f);
    float e = __expf(2.f * xa);
    return (e - 1.f) * __builtin_amdgcn_rcpf(e + 1.f);
}
__device__ __forceinline__ unsigned pk_rte(float a, float b) {
    union { _Float16 h[2]; unsigned u; } v;
    v.h[0] = (_Float16)a; v.h[1] = (_Float16)b; return v.u;
}
__device__ __forceinline__ half2_t h2(unsigned u) {
    return __builtin_bit_cast(half2_t, u);
}
__device__ __forceinline__ unsigned pkrtz(float a, float b) {
    return __builtin_bit_cast(unsigned, __builtin_amdgcn_cvt_pkrtz(a, b));
}

// ---------------- prep: pack weights + x window to f16 (R9 layout) ----------
__global__ __launch_bounds__(512) void wavenet_prep16(
    const float* __restrict__ x,
    const float* __restrict__ pre_w,
    const float* __restrict__ fw, const float* __restrict__ gw,
    const float* __restrict__ pw, unsigned* __restrict__ ws)
{
    int idx = blockIdx.x * 512 + threadIdx.x;
    if (idx >= XP_U32) return;
    unsigned v;
    if (idx < WTOT_U32) {
        int i = idx / WLAYER_U32;
        int r = idx - i * WLAYER_U32;
        if (r < 1024) {
            int kg = r >> 8, o = (r >> 2) & 63, e = r & 3;
            const float* p = pre_w + (i * 64 + o) * 32 + 8 * kg + 2 * e;
            v = pk_rte(p[0], p[1]);
        } else if (r < 9216) {
            const int isg = (r >= 5120);
            int e2 = r - (isg ? 5120 : 1024);
            int kb = e2 >> 8, o = (e2 >> 2) & 63, e = e2 & 3;
            int m = kb >> 2, h4g = kb & 3;
            int tap = m >> 1;
            int c = 32 * (m & 1) + 8 * h4g + 2 * e;
            const float* src = isg ? gw : fw;
            const float* p = src + ((i * 64 + o) * 64 + c) * 2 + tap;
            v = pk_rte(p[0], p[2]);   // (w[o][c][tap], w[o][c+1][tap])
        } else {
            int e3 = r - 9216;
            int kg = e3 >> 8, o = (e3 >> 2) & 63, e = e3 & 3;
            const float* p = pw + (i * 64 + o) * 64 + 8 * kg + 2 * e;
            v = pk_rte(p[0], p[1]);
        }
    } else {
        int e = idx - WTOT_U32;
        int b = e >> 13, r2 = e & 8191;
        int tw = r2 >> 4, cp = r2 & 15;
        const float* p = x + (size_t)(b * 32 + 2 * cp) * TFULL + WIN0 + tw;
        v = pk_rte(p[0], p[TFULL]);
    }
    ws[idx] = v;
}

// ---------------- layer-parallel all-MFMA kernel, 4 waves ----------------
// grid 2048 = layer(8) x bt(256); 256 threads; LDS 13824 B.
// Wave = o-tile mt (0..3); each wave covers BOTH col-halves nt=0,1.
// All A-fragments (P1 1 + P2 8 + P3 2) loaded up-front; L2 latency hides
// under P1's MFMAs; P2/P3 are pure LDS+MFMA with 4 independent acc chains.
__global__ __launch_bounds__(256, 4) void wavenet_mfma3(
    const unsigned* __restrict__ wsu,
    const float* __restrict__ pre_b,
    const float* __restrict__ filt_b, const float* __restrict__ gate_b,
    const float* __restrict__ post_b,
    unsigned* __restrict__ pout)
{
    __shared__ __align__(16) unsigned lds[LDS_U32];

    const int tid = threadIdx.x;
    const int i = blockIdx.x >> 8;
    const int bt = blockIdx.x & 255;
    const int b = bt >> 3;
    const int tile = bt & 7;
    const int dil = 1 << i;
    const int off1 = (dil < 32) ? dil : 32;
    const int t0 = TFULL - DEC + tile * 32;

    const int lane = tid & 63;
    const int mt = __builtin_amdgcn_readfirstlane(tid >> 6); // wave = o-tile 0..3
    const int h4 = lane >> 4;       // 0..3 (k-group)
    const int ln = lane & 15;       // row/col within tile

    const unsigned* xw = wsu + WTOT_U32 + b * 8192;
    const unsigned* wl = wsu + i * WLAYER_U32;

    // ---- preload ALL A-fragments (issued before any MFMA; hides L2 lat) ----
    f16x8 aPre = *(const f16x8*)(wl + (h4 * 64 + mt * 16 + ln) * 4);
    f16x8 af[4], ag[4], ap[2];
#pragma unroll
    for (int m = 0; m < 4; ++m) {
        const int kbg = 4 * m + h4;
        af[m] = *(const f16x8*)(wl + 1024 + (kbg * 64 + mt * 16 + ln) * 4);
        ag[m] = *(const f16x8*)(wl + 5120 + (kbg * 64 + mt * 16 + ln) * 4);
    }
#pragma unroll
    for (int ki = 0; ki < 2; ++ki) {
        const int kg = 4 * ki + h4;
        ap[ki] = *(const f16x8*)(wl + 9216 + (kg * 64 + mt * 16 + ln) * 4);
    }

    // ---- P1: h[o-tile mt][cw64] = relu(pre . x); 4 MFMAs ----
    {
        float4 pb4 = *(const float4*)(pre_b + i * 64 + mt * 16 + 4 * h4);
#pragma unroll
        for (int ct2 = 0; ct2 < 4; ++ct2) {
            const int cw = ct2 * 16 + ln;  // window col
            int ta = (dil >= 32) ? ((cw < 32) ? (t0 - dil + cw) : (t0 + cw - 32))
                                 : (t0 - dil + cw);
            const int tw = (ta - WIN0) & 511;   // wrap unused tail cols
            f16x8 bx = *(const f16x8*)(xw + tw * 16 + h4 * 4);
            f32x4 c = {0.f, 0.f, 0.f, 0.f};
            c = __builtin_amdgcn_mfma_f32_16x16x32_f16(aPre, bx, c, 0, 0, 0);
            // rows o = mt*16 + 4*h4 + reg, col cw
            uint2 hv;
            hv.x = pkrtz(fmaxf(c[0] + pb4.x, 0.f), fmaxf(c[1] + pb4.y, 0.f));
            hv.y = pkrtz(fmaxf(c[2] + pb4.z, 0.f), fmaxf(c[3] + pb4.w, 0.f));
            *(uint2*)&lds[cw * HSTR + mt * 8 + h4 * 2] = hv;
        }
    }
    __syncthreads();

    // ---- P2: F,G for both col-halves; pure LDS+MFMA, 4 acc chains ----
    {
        f32x4 cf[2], cg[2];
#pragma unroll
        for (int nt = 0; nt < 2; ++nt) {
            cf[nt] = (f32x4){0.f, 0.f, 0.f, 0.f};
            cg[nt] = (f32x4){0.f, 0.f, 0.f, 0.f};
        }
#pragma unroll
        for (int m = 0; m < 4; ++m) {
#pragma unroll
            for (int nt = 0; nt < 2; ++nt) {
                const int t = nt * 16 + ln;
                const int row = (m >> 1) ? (t + off1) : t;   // tap select
                uint4 bf4 = *(const uint4*)&lds[row * HSTR + 16 * (m & 1) + 4 * h4];
                f16x8 bfrag = __builtin_bit_cast(f16x8, bf4);
                cf[nt] = __builtin_amdgcn_mfma_f32_16x16x32_f16(af[m], bfrag, cf[nt], 0, 0, 0);
                cg[nt] = __builtin_amdgcn_mfma_f32_16x16x32_f16(ag[m], bfrag, cg[nt], 0, 0, 0);
            }
        }
        float4 fb = *(const float4*)(filt_b + i * 64 + mt * 16 + 4 * h4);
        float4 gb = *(const float4*)(gate_b + i * 64 + mt * 16 + 4 * h4);
#pragma unroll
        for (int nt = 0; nt < 2; ++nt) {
            const int t = nt * 16 + ln;
            float s0 = fast_tanh(cf[nt][0] + fb.x) * fmaxf(cg[nt][0] + gb.x, 0.f);
            float s1 = fast_tanh(cf[nt][1] + fb.y) * fmaxf(cg[nt][1] + gb.y, 0.f);
            float s2 = fast_tanh(cf[nt][2] + fb.z) * fmaxf(cg[nt][2] + gb.z, 0.f);
            float s3 = fast_tanh(cf[nt][3] + fb.w) * fmaxf(cg[nt][3] + gb.w, 0.f);
            uint2 sv;
            sv.x = pkrtz(s0, s1);
            sv.y = pkrtz(s2, s3);
            *(uint2*)&lds[HU + t * SSTR + mt * 8 + h4 * 2] = sv;
        }
    }
    __syncthreads();

    // ---- P3: P for both col-halves (K=64); coalesced uint2 partial write ----
    {
        float4 pb = *(const float4*)(post_b + i * 64 + mt * 16 + 4 * h4);
        unsigned* po = pout + (size_t)(i * 256 + bt) * 1024;
#pragma unroll
        for (int nt = 0; nt < 2; ++nt) {
            const int t = nt * 16 + ln;
            f32x4 cp = {0.f, 0.f, 0.f, 0.f};
#pragma unroll
            for (int ki = 0; ki < 2; ++ki) {
                const int kg = 4 * ki + h4;      // c0 = 8*kg
                f16x8 bs = *(const f16x8*)&lds[HU + t * SSTR + 4 * kg];
                cp = __builtin_amdgcn_mfma_f32_16x16x32_f16(ap[ki], bs, cp, 0, 0, 0);
            }
            // partial layout: [q16][t32][2] u32, q = o>>2 = mt*4+h4
            uint2 o2;
            o2.x = pkrtz(fmaxf(cp[0] + pb.x, 0.f), fmaxf(cp[1] + pb.y, 0.f));
            o2.y = pkrtz(fmaxf(cp[2] + pb.z, 0.f), fmaxf(cp[3] + pb.w, 0.f));
            *(uint2*)&po[(mt * 4 + h4) * 64 + 2 * t] = o2;
        }
    }
}

// ---------------- head: skip-sum + dense 64 -> 128 -> 1 ----------------
__global__ __launch_bounds__(512) void wavenet_head16(
    const unsigned* __restrict__ pin,
    const float* __restrict__ d1_w, const float* __restrict__ d1_b,
    const float* __restrict__ d2_w, const float* __restrict__ d2_b,
    float* __restrict__ out)
{
    __shared__ __align__(16) float accf[64 * 33];
    __shared__ float red[512];
    const int tid = threadIdx.x;
    const int bt = blockIdx.x;          // b*8 + tile
    const int q = tid >> 5, tt = tid & 31;

    float a[4] = {0.f, 0.f, 0.f, 0.f};
#pragma unroll
    for (int l = 0; l < 8; ++l) {
        const unsigned* p = pin + (size_t)(l * 256 + bt) * 1024;
        uint2 u = *(const uint2*)&p[q * 64 + 2 * tt];
        half2_t u0 = h2(u.x), u1 = h2(u.y);
        a[0] += (float)u0[0]; a[1] += (float)u0[1];
        a[2] += (float)u1[0]; a[3] += (float)u1[1];
    }
#pragma unroll
    for (int oo = 0; oo < 4; ++oo) accf[(4 * q + oo) * 33 + tt] = a[oo];
    __syncthreads();

    {
        const int pg = tid >> 5;  // 16 groups x 8 p
        float partial = 0.f;
#pragma unroll
        for (int pp = 0; pp < 8; ++pp) {
            const int p = pg * 8 + pp;
            float z = d1_b[p];
            const float4* w4 = (const float4*)(d1_w + p * 64);
#pragma unroll 4
            for (int c4 = 0; c4 < 16; ++c4) {
                float4 w = w4[c4];
                z = fmaf(w.x, accf[(c4 * 4 + 0) * 33 + tt], z);
                z = fmaf(w.y, accf[(c4 * 4 + 1) * 33 + tt], z);
                z = fmaf(w.z, accf[(c4 * 4 + 2) * 33 + tt], z);
                z = fmaf(w.w, accf[(c4 * 4 + 3) * 33 + tt], z);
            }
            partial = fmaf(d2_w[p], fmaxf(z, 0.f), partial);
        }
        red[pg * 32 + tt] = partial;
    }
    __syncthreads();
    if (tid < 32) {
        float sum = d2_b[0];
#pragma unroll
        for (int g = 0; g < 16; ++g) sum += red[g * 32 + tid];
        out[bt * 32 + tid] = fmaxf(sum, 0.f);
    }
}

// ================= fallback: fp32 fused (no ws) =================
#define HROW 164
#define SROW 33
__global__ __launch_bounds__(512) void wavenet_main(
    const float* __restrict__ x,
    const float* __restrict__ pre_w, const float* __restrict__ pre_b,
    const float* __restrict__ filt_w, const float* __restrict__ filt_b,
    const float* __restrict__ gate_w, const float* __restrict__ gate_b,
    const float* __restrict__ post_w, const float* __restrict__ post_b,
    const float* __restrict__ d1_w, const float* __restrict__ d1_b,
    const float* __restrict__ d2_w, const float* __restrict__ d2_b,
    float* __restrict__ out)
{
    __shared__ __align__(16) float h_s[64 * HROW];
    __shared__ __align__(16) float wbuf[20480];
    __shared__ __align__(16) float s_s[64 * SROW];
    const int tid = threadIdx.x;
    const int b = blockIdx.x >> 3;
    const int tile = blockIdx.x & 7;
    const int t0 = TFULL - DEC + tile * 32;
    const int lane = tid & 63;
    const int wv = __builtin_amdgcn_readfirstlane(tid >> 6);
    const int q = tid >> 5;
    const int tt = tid & 31;
    float accp[4] = {0.f, 0.f, 0.f, 0.f};
    for (int i = 0; i < 8; ++i) {
        const int dil = 1 << i;
        const int NC = 32 + dil;
        for (int m = tid; m < 8192; m += 512) {
            int c = m >> 7, rem = m & 127, o = rem >> 1, k = m & 1;
            wbuf[m] = filt_w[((i * 64 + o) * 64 + c) * 2 + k];
            wbuf[8192 + m] = gate_w[((i * 64 + o) * 64 + c) * 2 + k];
        }
        for (int m = tid; m < 4096; m += 512) {
            int c = m >> 6, o = m & 63;
            wbuf[16384 + m] = post_w[(i * 64 + o) * 64 + c];
        }
        __syncthreads();
        {
            const float* preb = pre_b + i * 64 + wv * 8;
            const float* prew = pre_w + (i * 64 + wv * 8) * 32;
            for (int col = lane; col < NC; col += 64) {
                int ta = t0 - dil + col;
                const float* xp = x + (size_t)b * 32 * TFULL + ta;
                float hacc[8];
#pragma unroll
                for (int r = 0; r < 8; ++r) hacc[r] = preb[r];
                for (int ci = 0; ci < 32; ++ci) {
                    float xv = xp[ci * TFULL];
#pragma unroll
                    for (int r = 0; r < 8; ++r)
                        hacc[r] = fmaf(prew[r * 32 + ci], xv, hacc[r]);
                }
#pragma unroll
                for (int r = 0; r < 8; ++r)
                    h_s[(wv * 8 + r) * HROW + col] = fmaxf(hacc[r], 0.f);
            }
        }
        __syncthreads();
        {
            float fa[4], ga[4];
#pragma unroll
            for (int oo = 0; oo < 4; ++oo) {
                fa[oo] = filt_b[i * 64 + q * 4 + oo];
                ga[oo] = gate_b[i * 64 + q * 4 + oo];
            }
            const float4* fw4 = (const float4*)wbuf;
            const float4* gw4 = (const float4*)(wbuf + 8192);
            const float* hrow0 = h_s + tt;
            const float* hrow1 = h_s + tt + dil;
#pragma unroll 4
            for (int c = 0; c < 64; ++c) {
                float4 f0 = fw4[c * 32 + q * 2];
                float4 f1 = fw4[c * 32 + q * 2 + 1];
                float4 g0 = gw4[c * 32 + q * 2];
                float4 g1 = gw4[c * 32 + q * 2 + 1];
                float h0 = hrow0[c * HROW];
                float h1 = hrow1[c * HROW];
                fa[0] = fmaf(f0.x, h0, fmaf(f0.y, h1, fa[0]));
                fa[1] = fmaf(f0.z, h0, fmaf(f0.w, h1, fa[1]));
                fa[2] = fmaf(f1.x, h0, fmaf(f1.y, h1, fa[2]));
                fa[3] = fmaf(f1.z, h0, fmaf(f1.w, h1, fa[3]));
                ga[0] = fmaf(g0.x, h0, fmaf(g0.y, h1, ga[0]));
                ga[1] = fmaf(g0.z, h0, fmaf(g0.w, h1, ga[1]));
                ga[2] = fmaf(g1.x, h0, fmaf(g1.y, h1, ga[2]));
                ga[3] = fmaf(g1.z, h0, fmaf(g1.w, h1, ga[3]));
            }
#pragma unroll
            for (int oo = 0; oo < 4; ++oo)
                s_s[(q * 4 + oo) * SROW + tt] = fast_tanh(fa[oo]) * fmaxf(ga[oo], 0.f);
        }
        __syncthreads();
        {
            float pa[4];
#pragma unroll
            for (int oo = 0; oo < 4; ++oo) pa[oo] = post_b[i * 64 + q * 4 + oo];
            const float4* pw4 = (const float4*)(wbuf + 16384);
#pragma unroll 4
            for (int c = 0; c < 64; ++c) {
                float4 pv = pw4[c * 16 + q];
                float sv = s_s[c * SROW + tt];
                pa[0] = fmaf(pv.x, sv, pa[0]);
                pa[1] = fmaf(pv.y, sv, pa[1]);
                pa[2] = fmaf(pv.z, sv, pa[2]);
                pa[3] = fmaf(pv.w, sv, pa[3]);
            }
#pragma unroll
            for (int oo = 0; oo < 4; ++oo) accp[oo] += fmaxf(pa[oo], 0.f);
        }
        __syncthreads();
    }
#pragma unroll
    for (int oo = 0; oo < 4; ++oo) s_s[(q * 4 + oo) * SROW + tt] = accp[oo];
    __syncthreads();
    {
        const int pg = tid >> 5;
        float partial = 0.f;
#pragma unroll
        for (int pp = 0; pp < 8; ++pp) {
            const int p = pg * 8 + pp;
            float z = d1_b[p];
            const float4* w4 = (const float4*)(d1_w + p * 64);
#pragma unroll 4
            for (int c4 = 0; c4 < 16; ++c4) {
                float4 w = w4[c4];
                z = fmaf(w.x, s_s[(c4 * 4 + 0) * SROW + tt], z);
                z = fmaf(w.y, s_s[(c4 * 4 + 1) * SROW + tt], z);
                z = fmaf(w.z, s_s[(c4 * 4 + 2) * SROW + tt], z);
                z = fmaf(w.w, s_s[(c4 * 4 + 3) * SROW + tt], z);
            }
            partial = fmaf(d2_w[p], fmaxf(z, 0.f), partial);
        }
        h_s[pg * 32 + tt] = partial;
    }
    __syncthreads();
    if (tid < 32) {
        float sum = d2_b[0];
#pragma unroll
        for (int g = 0; g < 16; ++g) sum += h_s[g * 32 + tid];
        out[b * DEC + tile * 32 + tid] = fmaxf(sum, 0.f);
    }
}

extern "C" void kernel_launch(void* const* d_in, const int* in_sizes, int n_in,
                              void* d_out, int out_size, void* d_ws, size_t ws_size,
                              hipStream_t stream)
{
    const float* x      = (const float*)d_in[0];
    const float* pre_w  = (const float*)d_in[1];
    const float* pre_b  = (const float*)d_in[2];
    const float* filt_w = (const float*)d_in[3];
    const float* filt_b = (const float*)d_in[4];
    const float* gate_w = (const float*)d_in[5];
    const float* gate_b = (const float*)d_in[6];
    const float* post_w = (const float*)d_in[7];
    const float* post_b = (const float*)d_in[8];
    const float* d1_w   = (const float*)d_in[9];
    const float* d1_b   = (const float*)d_in[10];
    const float* d2_w   = (const float*)d_in[11];
    const float* d2_b   = (const float*)d_in[12];
    float* out = (float*)d_out;

    if (ws_size >= WS_NEED2) {
        unsigned* ws = (unsigned*)d_ws;
        unsigned* part = ws + XP_U32;
        wavenet_prep16<<<688, 512, 0, stream>>>(x, pre_w, filt_w, gate_w, post_w, ws);
        wavenet_mfma3<<<2048, 256, 0, stream>>>(
            ws, pre_b, filt_b, gate_b, post_b, part);
        wavenet_head16<<<256, 512, 0, stream>>>(
            part, d1_w, d1_b, d2_w, d2_b, out);
    } else {
        wavenet_main<<<256, 512, 0, stream>>>(
            x, pre_w, pre_b, filt_w, filt_b, gate_w, gate_b, post_w, post_b,
            d1_w, d1_b, d2_w, d2_b, out);
    }
}

// Round 12
// 26.348 us; speedup vs baseline: 1.5003x; 1.0531x over previous
//
#include <hip/hip_runtime.h>

typedef _Float16 half2_t __attribute__((ext_vector_type(2)));
typedef _Float16 f16x8 __attribute__((ext_vector_type(8)));
typedef float f32x4 __attribute__((ext_vector_type(4)));

#define DEC 256
#define TFULL 4096
#define WIN0 3584               // x window start (t0min-128 = 3712 >= 3584)
#define WLAYER_U32 11264        // preA 1024 + f 4096 + g 4096 + p 2048
#define WTOT_U32 (8 * WLAYER_U32)          // 90112
#define X16_U32 (32 * 512 * 16)            // 262144, x16t[b][tw512][cp16]
#define P_U32 (8 * 256 * 1024)             // skip partials, f16x2 packed
#define XP_U32 (WTOT_U32 + X16_U32)        // 352256
#define WS_NEED2 ((size_t)(XP_U32 + P_U32) * 4)

#define HSTR 36                 // h LDS row stride (u32), mult of 4 for b128
#define SSTR 36                 // s LDS row stride (u32)
#define HU (64 * HSTR)          // 2304 u32
#define LDS_U32 (HU + 32 * SSTR)  // 3456 u32 = 13824 B

__device__ __forceinline__ float fast_tanh(float x) {
    float xa = fminf(fmaxf(x, -10.f), 10.f);
    float e = __expf(2.f * xa);
    return (e - 1.f) * __builtin_amdgcn_rcpf(e + 1.f);
}
__device__ __forceinline__ unsigned pk_rte(float a, float b) {
    union { _Float16 h[2]; unsigned u; } v;
    v.h[0] = (_Float16)a; v.h[1] = (_Float16)b; return v.u;
}
__device__ __forceinline__ half2_t h2(unsigned u) {
    return __builtin_bit_cast(half2_t, u);
}
__device__ __forceinline__ unsigned pkrtz(float a, float b) {
    return __builtin_bit_cast(unsigned, __builtin_amdgcn_cvt_pkrtz(a, b));
}

// ---------------- prep: pack weights + x window to f16 (R9 layout) ----------
// x16 region: only tw in [128,512) is ever consumed (window analysis); skip rest.
__global__ __launch_bounds__(512) void wavenet_prep16(
    const float* __restrict__ x,
    const float* __restrict__ pre_w,
    const float* __restrict__ fw, const float* __restrict__ gw,
    const float* __restrict__ pw, unsigned* __restrict__ ws)
{
    int idx = blockIdx.x * 512 + threadIdx.x;
    if (idx >= XP_U32) return;
    unsigned v;
    if (idx < WTOT_U32) {
        int i = idx / WLAYER_U32;
        int r = idx - i * WLAYER_U32;
        if (r < 1024) {
            int kg = r >> 8, o = (r >> 2) & 63, e = r & 3;
            const float* p = pre_w + (i * 64 + o) * 32 + 8 * kg + 2 * e;
            v = pk_rte(p[0], p[1]);
        } else if (r < 9216) {
            const int isg = (r >= 5120);
            int e2 = r - (isg ? 5120 : 1024);
            int kb = e2 >> 8, o = (e2 >> 2) & 63, e = e2 & 3;
            int m = kb >> 2, h4g = kb & 3;
            int tap = m >> 1;
            int c = 32 * (m & 1) + 8 * h4g + 2 * e;
            const float* src = isg ? gw : fw;
            const float* p = src + ((i * 64 + o) * 64 + c) * 2 + tap;
            v = pk_rte(p[0], p[2]);   // (w[o][c][tap], w[o][c+1][tap])
        } else {
            int e3 = r - 9216;
            int kg = e3 >> 8, o = (e3 >> 2) & 63, e = e3 & 3;
            const float* p = pw + (i * 64 + o) * 64 + 8 * kg + 2 * e;
            v = pk_rte(p[0], p[1]);
        }
    } else {
        int e = idx - WTOT_U32;
        int b = e >> 13, r2 = e & 8191;
        int tw = r2 >> 4, cp = r2 & 15;
        if (tw < 128) return;          // never consumed by valid cols
        const float* p = x + (size_t)(b * 32 + 2 * cp) * TFULL + WIN0 + tw;
        v = pk_rte(p[0], p[TFULL]);
    }
    ws[idx] = v;
}

// ---------------- layer-parallel all-MFMA kernel, 4 waves (R11) ------------
// grid 2048 = layer(8) x bt(256); 256 threads; LDS 13824 B.
// Wave = o-tile mt (0..3); each wave covers BOTH col-halves nt=0,1.
__global__ __launch_bounds__(256, 4) void wavenet_mfma3(
    const unsigned* __restrict__ wsu,
    const float* __restrict__ pre_b,
    const float* __restrict__ filt_b, const float* __restrict__ gate_b,
    const float* __restrict__ post_b,
    unsigned* __restrict__ pout)
{
    __shared__ __align__(16) unsigned lds[LDS_U32];

    const int tid = threadIdx.x;
    const int i = blockIdx.x >> 8;
    const int bt = blockIdx.x & 255;
    const int b = bt >> 3;
    const int tile = bt & 7;
    const int dil = 1 << i;
    const int off1 = (dil < 32) ? dil : 32;
    const int t0 = TFULL - DEC + tile * 32;

    const int lane = tid & 63;
    const int mt = __builtin_amdgcn_readfirstlane(tid >> 6); // wave = o-tile 0..3
    const int h4 = lane >> 4;       // 0..3 (k-group)
    const int ln = lane & 15;       // row/col within tile

    const unsigned* xw = wsu + WTOT_U32 + b * 8192;
    const unsigned* wl = wsu + i * WLAYER_U32;

    // ---- preload ALL A-fragments (issued before any MFMA; hides L2 lat) ----
    f16x8 aPre = *(const f16x8*)(wl + (h4 * 64 + mt * 16 + ln) * 4);
    f16x8 af[4], ag[4], ap[2];
#pragma unroll
    for (int m = 0; m < 4; ++m) {
        const int kbg = 4 * m + h4;
        af[m] = *(const f16x8*)(wl + 1024 + (kbg * 64 + mt * 16 + ln) * 4);
        ag[m] = *(const f16x8*)(wl + 5120 + (kbg * 64 + mt * 16 + ln) * 4);
    }
#pragma unroll
    for (int ki = 0; ki < 2; ++ki) {
        const int kg = 4 * ki + h4;
        ap[ki] = *(const f16x8*)(wl + 9216 + (kg * 64 + mt * 16 + ln) * 4);
    }

    // ---- P1: h[o-tile mt][cw64] = relu(pre . x); 4 MFMAs ----
    {
        float4 pb4 = *(const float4*)(pre_b + i * 64 + mt * 16 + 4 * h4);
#pragma unroll
        for (int ct2 = 0; ct2 < 4; ++ct2) {
            const int cw = ct2 * 16 + ln;  // window col
            int ta = (dil >= 32) ? ((cw < 32) ? (t0 - dil + cw) : (t0 + cw - 32))
                                 : (t0 - dil + cw);
            const int tw = (ta - WIN0) & 511;   // wrap unused tail cols
            f16x8 bx = *(const f16x8*)(xw + tw * 16 + h4 * 4);
            f32x4 c = {0.f, 0.f, 0.f, 0.f};
            c = __builtin_amdgcn_mfma_f32_16x16x32_f16(aPre, bx, c, 0, 0, 0);
            uint2 hv;
            hv.x = pkrtz(fmaxf(c[0] + pb4.x, 0.f), fmaxf(c[1] + pb4.y, 0.f));
            hv.y = pkrtz(fmaxf(c[2] + pb4.z, 0.f), fmaxf(c[3] + pb4.w, 0.f));
            *(uint2*)&lds[cw * HSTR + mt * 8 + h4 * 2] = hv;
        }
    }
    __syncthreads();

    // ---- P2: F,G for both col-halves; pure LDS+MFMA, 4 acc chains ----
    {
        f32x4 cf[2], cg[2];
#pragma unroll
        for (int nt = 0; nt < 2; ++nt) {
            cf[nt] = (f32x4){0.f, 0.f, 0.f, 0.f};
            cg[nt] = (f32x4){0.f, 0.f, 0.f, 0.f};
        }
#pragma unroll
        for (int m = 0; m < 4; ++m) {
#pragma unroll
            for (int nt = 0; nt < 2; ++nt) {
                const int t = nt * 16 + ln;
                const int row = (m >> 1) ? (t + off1) : t;   // tap select
                uint4 bf4 = *(const uint4*)&lds[row * HSTR + 16 * (m & 1) + 4 * h4];
                f16x8 bfrag = __builtin_bit_cast(f16x8, bf4);
                cf[nt] = __builtin_amdgcn_mfma_f32_16x16x32_f16(af[m], bfrag, cf[nt], 0, 0, 0);
                cg[nt] = __builtin_amdgcn_mfma_f32_16x16x32_f16(ag[m], bfrag, cg[nt], 0, 0, 0);
            }
        }
        float4 fb = *(const float4*)(filt_b + i * 64 + mt * 16 + 4 * h4);
        float4 gb = *(const float4*)(gate_b + i * 64 + mt * 16 + 4 * h4);
#pragma unroll
        for (int nt = 0; nt < 2; ++nt) {
            const int t = nt * 16 + ln;
            float s0 = fast_tanh(cf[nt][0] + fb.x) * fmaxf(cg[nt][0] + gb.x, 0.f);
            float s1 = fast_tanh(cf[nt][1] + fb.y) * fmaxf(cg[nt][1] + gb.y, 0.f);
            float s2 = fast_tanh(cf[nt][2] + fb.z) * fmaxf(cg[nt][2] + gb.z, 0.f);
            float s3 = fast_tanh(cf[nt][3] + fb.w) * fmaxf(cg[nt][3] + gb.w, 0.f);
            uint2 sv;
            sv.x = pkrtz(s0, s1);
            sv.y = pkrtz(s2, s3);
            *(uint2*)&lds[HU + t * SSTR + mt * 8 + h4 * 2] = sv;
        }
    }
    __syncthreads();

    // ---- P3: P for both col-halves (K=64); coalesced uint2 partial write ----
    {
        float4 pb = *(const float4*)(post_b + i * 64 + mt * 16 + 4 * h4);
        unsigned* po = pout + (size_t)(i * 256 + bt) * 1024;
#pragma unroll
        for (int nt = 0; nt < 2; ++nt) {
            const int t = nt * 16 + ln;
            f32x4 cp = {0.f, 0.f, 0.f, 0.f};
#pragma unroll
            for (int ki = 0; ki < 2; ++ki) {
                const int kg = 4 * ki + h4;      // c0 = 8*kg
                f16x8 bs = *(const f16x8*)&lds[HU + t * SSTR + 4 * kg];
                cp = __builtin_amdgcn_mfma_f32_16x16x32_f16(ap[ki], bs, cp, 0, 0, 0);
            }
            // partial layout: [q16][t32][2] u32, q = o>>2 = mt*4+h4
            uint2 o2;
            o2.x = pkrtz(fmaxf(cp[0] + pb.x, 0.f), fmaxf(cp[1] + pb.y, 0.f));
            o2.y = pkrtz(fmaxf(cp[2] + pb.z, 0.f), fmaxf(cp[3] + pb.w, 0.f));
            *(uint2*)&po[(mt * 4 + h4) * 64 + 2 * t] = o2;
        }
    }
}

// ---------------- head: skip-sum + dense 64 -> 128 -> 1, 16 cols/block ------
// grid 512 = bt(256) x half(2); 512 threads; 2 blocks/CU.
__global__ __launch_bounds__(512) void wavenet_head16(
    const unsigned* __restrict__ pin,
    const float* __restrict__ d1_w, const float* __restrict__ d1_b,
    const float* __restrict__ d2_w, const float* __restrict__ d2_b,
    float* __restrict__ out)
{
    __shared__ __align__(16) float accf[64 * 20];   // [c64][tc16] stride 20
    __shared__ __align__(16) float zbuf[128 * 16];  // [p128][tc16]
    __shared__ float red[16 * 8];
    const int tid = threadIdx.x;
    const int bt = blockIdx.x >> 1;
    const int half = blockIdx.x & 1;

    // ---- A: skip-sum (8 layers) for 16 cols; o = 4q+oo ----
    if (tid < 256) {
        const int q = tid >> 4, tc = tid & 15;
        const int t = half * 16 + tc;
        float a0 = 0.f, a1 = 0.f, a2 = 0.f, a3 = 0.f;
#pragma unroll
        for (int l = 0; l < 8; ++l) {
            const unsigned* p = pin + (size_t)(l * 256 + bt) * 1024;
            uint2 u = *(const uint2*)&p[q * 64 + 2 * t];
            half2_t u0 = h2(u.x), u1 = h2(u.y);
            a0 += (float)u0[0]; a1 += (float)u0[1];
            a2 += (float)u1[0]; a3 += (float)u1[1];
        }
        accf[(4 * q + 0) * 20 + tc] = a0;
        accf[(4 * q + 1) * 20 + tc] = a1;
        accf[(4 * q + 2) * 20 + tc] = a2;
        accf[(4 * q + 3) * 20 + tc] = a3;
    }
    __syncthreads();

    // ---- B: d1 (128x64) x acc, 4 cols/thread (256 fma) + relu + d2 scale ----
    {
        const int p = tid >> 2, tc0 = (tid & 3) * 4;
        float z0 = d1_b[p], z1 = z0, z2 = z0, z3 = z0;
        const float4* w4 = (const float4*)(d1_w + p * 64);
#pragma unroll 4
        for (int c4 = 0; c4 < 16; ++c4) {
            float4 w = w4[c4];
#pragma unroll
            for (int cc = 0; cc < 4; ++cc) {
                const float wv = (cc == 0) ? w.x : (cc == 1) ? w.y : (cc == 2) ? w.z : w.w;
                float4 av = *(const float4*)&accf[(c4 * 4 + cc) * 20 + tc0];
                z0 = fmaf(wv, av.x, z0);
                z1 = fmaf(wv, av.y, z1);
                z2 = fmaf(wv, av.z, z2);
                z3 = fmaf(wv, av.w, z3);
            }
        }
        const float dw = d2_w[p];
        float4 zo;
        zo.x = fmaxf(z0, 0.f) * dw;
        zo.y = fmaxf(z1, 0.f) * dw;
        zo.z = fmaxf(z2, 0.f) * dw;
        zo.w = fmaxf(z3, 0.f) * dw;
        *(float4*)&zbuf[p * 16 + tc0] = zo;
    }
    __syncthreads();

    // ---- C: reduce 128 p per col ----
    if (tid < 128) {
        const int tc = tid >> 3, seg = tid & 7;
        float sum = 0.f;
#pragma unroll
        for (int k = 0; k < 16; ++k)
            sum += zbuf[(seg * 16 + k) * 16 + tc];
        red[tc * 8 + seg] = sum;
    }
    __syncthreads();
    if (tid < 16) {
        float sum = d2_b[0];
#pragma unroll
        for (int g = 0; g < 8; ++g) sum += red[tid * 8 + g];
        out[bt * 32 + half * 16 + tid] = fmaxf(sum, 0.f);
    }
}

// ================= fallback: fp32 fused (no ws) =================
#define HROW 164
#define SROW 33
__global__ __launch_bounds__(512) void wavenet_main(
    const float* __restrict__ x,
    const float* __restrict__ pre_w, const float* __restrict__ pre_b,
    const float* __restrict__ filt_w, const float* __restrict__ filt_b,
    const float* __restrict__ gate_w, const float* __restrict__ gate_b,
    const float* __restrict__ post_w, const float* __restrict__ post_b,
    const float* __restrict__ d1_w, const float* __restrict__ d1_b,
    const float* __restrict__ d2_w, const float* __restrict__ d2_b,
    float* __restrict__ out)
{
    __shared__ __align__(16) float h_s[64 * HROW];
    __shared__ __align__(16) float wbuf[20480];
    __shared__ __align__(16) float s_s[64 * SROW];
    const int tid = threadIdx.x;
    const int b = blockIdx.x >> 3;
    const int tile = blockIdx.x & 7;
    const int t0 = TFULL - DEC + tile * 32;
    const int lane = tid & 63;
    const int wv = __builtin_amdgcn_readfirstlane(tid >> 6);
    const int q = tid >> 5;
    const int tt = tid & 31;
    float accp[4] = {0.f, 0.f, 0.f, 0.f};
    for (int i = 0; i < 8; ++i) {
        const int dil = 1 << i;
        const int NC = 32 + dil;
        for (int m = tid; m < 8192; m += 512) {
            int c = m >> 7, rem = m & 127, o = rem >> 1, k = m & 1;
            wbuf[m] = filt_w[((i * 64 + o) * 64 + c) * 2 + k];
            wbuf[8192 + m] = gate_w[((i * 64 + o) * 64 + c) * 2 + k];
        }
        for (int m = tid; m < 4096; m += 512) {
            int c = m >> 6, o = m & 63;
            wbuf[16384 + m] = post_w[(i * 64 + o) * 64 + c];
        }
        __syncthreads();
        {
            const float* preb = pre_b + i * 64 + wv * 8;
            const float* prew = pre_w + (i * 64 + wv * 8) * 32;
            for (int col = lane; col < NC; col += 64) {
                int ta = t0 - dil + col;
                const float* xp = x + (size_t)b * 32 * TFULL + ta;
                float hacc[8];
#pragma unroll
                for (int r = 0; r < 8; ++r) hacc[r] = preb[r];
                for (int ci = 0; ci < 32; ++ci) {
                    float xv = xp[ci * TFULL];
#pragma unroll
                    for (int r = 0; r < 8; ++r)
                        hacc[r] = fmaf(prew[r * 32 + ci], xv, hacc[r]);
                }
#pragma unroll
                for (int r = 0; r < 8; ++r)
                    h_s[(wv * 8 + r) * HROW + col] = fmaxf(hacc[r], 0.f);
            }
        }
        __syncthreads();
        {
            float fa[4], ga[4];
#pragma unroll
            for (int oo = 0; oo < 4; ++oo) {
                fa[oo] = filt_b[i * 64 + q * 4 + oo];
                ga[oo] = gate_b[i * 64 + q * 4 + oo];
            }
            const float4* fw4 = (const float4*)wbuf;
            const float4* gw4 = (const float4*)(wbuf + 8192);
            const float* hrow0 = h_s + tt;
            const float* hrow1 = h_s + tt + dil;
#pragma unroll 4
            for (int c = 0; c < 64; ++c) {
                float4 f0 = fw4[c * 32 + q * 2];
                float4 f1 = fw4[c * 32 + q * 2 + 1];
                float4 g0 = gw4[c * 32 + q * 2];
                float4 g1 = gw4[c * 32 + q * 2 + 1];
                float h0 = hrow0[c * HROW];
                float h1 = hrow1[c * HROW];
                fa[0] = fmaf(f0.x, h0, fmaf(f0.y, h1, fa[0]));
                fa[1] = fmaf(f0.z, h0, fmaf(f0.w, h1, fa[1]));
                fa[2] = fmaf(f1.x, h0, fmaf(f1.y, h1, fa[2]));
                fa[3] = fmaf(f1.z, h0, fmaf(f1.w, h1, fa[3]));
                ga[0] = fmaf(g0.x, h0, fmaf(g0.y, h1, ga[0]));
                ga[1] = fmaf(g0.z, h0, fmaf(g0.w, h1, ga[1]));
                ga[2] = fmaf(g1.x, h0, fmaf(g1.y, h1, ga[2]));
                ga[3] = fmaf(g1.z, h0, fmaf(g1.w, h1, ga[3]));
            }
#pragma unroll
            for (int oo = 0; oo < 4; ++oo)
                s_s[(q * 4 + oo) * SROW + tt] = fast_tanh(fa[oo]) * fmaxf(ga[oo], 0.f);
        }
        __syncthreads();
        {
            float pa[4];
#pragma unroll
            for (int oo = 0; oo < 4; ++oo) pa[oo] = post_b[i * 64 + q * 4 + oo];
            const float4* pw4 = (const float4*)(wbuf + 16384);
#pragma unroll 4
            for (int c = 0; c < 64; ++c) {
                float4 pv = pw4[c * 16 + q];
                float sv = s_s[c * SROW + tt];
                pa[0] = fmaf(pv.x, sv, pa[0]);
                pa[1] = fmaf(pv.y, sv, pa[1]);
                pa[2] = fmaf(pv.z, sv, pa[2]);
                pa[3] = fmaf(pv.w, sv, pa[3]);
            }
#pragma unroll
            for (int oo = 0; oo < 4; ++oo) accp[oo] += fmaxf(pa[oo], 0.f);
        }
        __syncthreads();
    }
#pragma unroll
    for (int oo = 0; oo < 4; ++oo) s_s[(q * 4 + oo) * SROW + tt] = accp[oo];
    __syncthreads();
    {
        const int pg = tid >> 5;
        float partial = 0.f;
#pragma unroll
        for (int pp = 0; pp < 8; ++pp) {
            const int p = pg * 8 + pp;
            float z = d1_b[p];
            const float4* w4 = (const float4*)(d1_w + p * 64);
#pragma unroll 4
            for (int c4 = 0; c4 < 16; ++c4) {
                float4 w = w4[c4];
                z = fmaf(w.x, s_s[(c4 * 4 + 0) * SROW + tt], z);
                z = fmaf(w.y, s_s[(c4 * 4 + 1) * SROW + tt], z);
                z = fmaf(w.z, s_s[(c4 * 4 + 2) * SROW + tt], z);
                z = fmaf(w.w, s_s[(c4 * 4 + 3) * SROW + tt], z);
            }
            partial = fmaf(d2_w[p], fmaxf(z, 0.f), partial);
        }
        h_s[pg * 32 + tt] = partial;
    }
    __syncthreads();
    if (tid < 32) {
        float sum = d2_b[0];
#pragma unroll
        for (int g = 0; g < 16; ++g) sum += h_s[g * 32 + tid];
        out[b * DEC + tile * 32 + tid] = fmaxf(sum, 0.f);
    }
}

extern "C" void kernel_launch(void* const* d_in, const int* in_sizes, int n_in,
                              void* d_out, int out_size, void* d_ws, size_t ws_size,
                              hipStream_t stream)
{
    const float* x      = (const float*)d_in[0];
    const float* pre_w  = (const float*)d_in[1];
    const float* pre_b  = (const float*)d_in[2];
    const float* filt_w = (const float*)d_in[3];
    const float* filt_b = (const float*)d_in[4];
    const float* gate_w = (const float*)d_in[5];
    const float* gate_b = (const float*)d_in[6];
    const float* post_w = (const float*)d_in[7];
    const float* post_b = (const float*)d_in[8];
    const float* d1_w   = (const float*)d_in[9];
    const float* d1_b   = (const float*)d_in[10];
    const float* d2_w   = (const float*)d_in[11];
    const float* d2_b   = (const float*)d_in[12];
    float* out = (float*)d_out;

    if (ws_size >= WS_NEED2) {
        unsigned* ws = (unsigned*)d_ws;
        unsigned* part = ws + XP_U32;
        wavenet_prep16<<<688, 512, 0, stream>>>(x, pre_w, filt_w, gate_w, post_w, ws);
        wavenet_mfma3<<<2048, 256, 0, stream>>>(
            ws, pre_b, filt_b, gate_b, post_b, part);
        wavenet_head16<<<512, 512, 0, stream>>>(
            part, d1_w, d1_b, d2_w, d2_b, out);
    } else {
        wavenet_main<<<256, 512, 0, stream>>>(
            x, pre_w, pre_b, filt_w, filt_b, gate_w, gate_b, post_w, post_b,
            d1_w, d1_b, d2_w, d2_b, out);
    }
}

// Round 13
// 25.544 us; speedup vs baseline: 1.5475x; 1.0315x over previous
//
#include <hip/hip_runtime.h>

typedef _Float16 half2_t __attribute__((ext_vector_type(2)));
typedef _Float16 f16x8 __attribute__((ext_vector_type(8)));
typedef float f32x4 __attribute__((ext_vector_type(4)));

#define DEC 256
#define TFULL 4096
#define WIN0 3584               // x window start (t0min-128 = 3712 >= 3584)
#define WLAYER_U32 11264        // preA 1024 + f 4096 + g 4096 + p 2048
#define WTOT_U32 (8 * WLAYER_U32)          // 90112
#define X16_U32 (32 * 512 * 16)            // 262144, x16t[b][tw512][cp16]
#define P_U32 (8 * 256 * 1024)             // skip partials, f16x2 packed
#define XP_U32 (WTOT_U32 + X16_U32)        // 352256
#define WS_NEED2 ((size_t)(XP_U32 + P_U32) * 4)

#define HSTR 36                 // h LDS row stride (u32), mult of 4 for b128
#define SSTR 36                 // s LDS row stride (u32)
#define HU (64 * HSTR)          // 2304 u32
#define LDS_U32 (HU + 32 * SSTR)  // 3456 u32 = 13824 B

__device__ __forceinline__ float fast_tanh(float x) {
    float xa = fminf(fmaxf(x, -10.f), 10.f);
    float e = __expf(2.f * xa);
    return (e - 1.f) * __builtin_amdgcn_rcpf(e + 1.f);
}
__device__ __forceinline__ unsigned pk_rte(float a, float b) {
    union { _Float16 h[2]; unsigned u; } v;
    v.h[0] = (_Float16)a; v.h[1] = (_Float16)b; return v.u;
}
__device__ __forceinline__ half2_t h2(unsigned u) {
    return __builtin_bit_cast(half2_t, u);
}
__device__ __forceinline__ unsigned pkrtz(float a, float b) {
    return __builtin_bit_cast(unsigned, __builtin_amdgcn_cvt_pkrtz(a, b));
}

// ---------------- prep: pack weights + x window to f16 (R9 layout) ----------
// x16 region: coalesced reads (lane ~ tw), strided writes; tw<128 skipped
// (window analysis: only tw in [128,512) is ever consumed).
__global__ __launch_bounds__(512) void wavenet_prep16(
    const float* __restrict__ x,
    const float* __restrict__ pre_w,
    const float* __restrict__ fw, const float* __restrict__ gw,
    const float* __restrict__ pw, unsigned* __restrict__ ws)
{
    int idx = blockIdx.x * 512 + threadIdx.x;
    if (idx >= XP_U32) return;
    unsigned v;
    int dst = idx;
    if (idx < WTOT_U32) {
        int i = idx / WLAYER_U32;
        int r = idx - i * WLAYER_U32;
        if (r < 1024) {
            int kg = r >> 8, o = (r >> 2) & 63, e = r & 3;
            const float* p = pre_w + (i * 64 + o) * 32 + 8 * kg + 2 * e;
            v = pk_rte(p[0], p[1]);
        } else if (r < 9216) {
            const int isg = (r >= 5120);
            int e2 = r - (isg ? 5120 : 1024);
            int kb = e2 >> 8, o = (e2 >> 2) & 63, e = e2 & 3;
            int m = kb >> 2, h4g = kb & 3;
            int tap = m >> 1;
            int c = 32 * (m & 1) + 8 * h4g + 2 * e;
            const float* src = isg ? gw : fw;
            const float* p = src + ((i * 64 + o) * 64 + c) * 2 + tap;
            v = pk_rte(p[0], p[2]);   // (w[o][c][tap], w[o][c+1][tap])
        } else {
            int e3 = r - 9216;
            int kg = e3 >> 8, o = (e3 >> 2) & 63, e = e3 & 3;
            const float* p = pw + (i * 64 + o) * 64 + 8 * kg + 2 * e;
            v = pk_rte(p[0], p[1]);
        }
    } else {
        int e = idx - WTOT_U32;
        int b = e >> 13, r2 = e & 8191;
        int cp = r2 >> 9, tw = r2 & 511;   // lane ~ tw -> coalesced x reads
        if (tw < 128) return;              // never consumed by valid cols
        const float* p = x + (size_t)(b * 32 + 2 * cp) * TFULL + WIN0 + tw;
        v = pk_rte(p[0], p[TFULL]);
        dst = WTOT_U32 + b * 8192 + tw * 16 + cp;
    }
    ws[dst] = v;
}

// ---------------- layer-parallel all-MFMA kernel, 2 bt-tiles/block ----------
// grid 1024 = layer(8) x btp(128); 256 threads; LDS 13824 B.
// Wave = o-tile mt (0..3). A-fragments + biases loaded ONCE, reused for both
// bt tiles; per tile {P1, bar, P2, bar, P3} (no extra barriers needed:
// P1b's h-writes conflict with nothing live; P3a's s-reads finish before the
// bar that precedes P2b's s-writes).
__global__ __launch_bounds__(256, 4) void wavenet_mfma4(
    const unsigned* __restrict__ wsu,
    const float* __restrict__ pre_b,
    const float* __restrict__ filt_b, const float* __restrict__ gate_b,
    const float* __restrict__ post_b,
    unsigned* __restrict__ pout)
{
    __shared__ __align__(16) unsigned lds[LDS_U32];

    const int tid = threadIdx.x;
    const int i = blockIdx.x >> 7;
    const int btp = blockIdx.x & 127;
    const int dil = 1 << i;
    const int off1 = (dil < 32) ? dil : 32;
    const int nct = (dil < 32) ? 3 : 4;   // h cols needed: 32+dil <= 48 for dil<32

    const int lane = tid & 63;
    const int mt = __builtin_amdgcn_readfirstlane(tid >> 6); // wave = o-tile 0..3
    const int h4 = lane >> 4;       // 0..3 (k-group)
    const int ln = lane & 15;       // row/col within tile

    const unsigned* wl = wsu + i * WLAYER_U32;

    // ---- preload ALL A-fragments + biases once (reused for both tiles) ----
    f16x8 aPre = *(const f16x8*)(wl + (h4 * 64 + mt * 16 + ln) * 4);
    f16x8 af[4], ag[4], ap[2];
#pragma unroll
    for (int m = 0; m < 4; ++m) {
        const int kbg = 4 * m + h4;
        af[m] = *(const f16x8*)(wl + 1024 + (kbg * 64 + mt * 16 + ln) * 4);
        ag[m] = *(const f16x8*)(wl + 5120 + (kbg * 64 + mt * 16 + ln) * 4);
    }
#pragma unroll
    for (int ki = 0; ki < 2; ++ki) {
        const int kg = 4 * ki + h4;
        ap[ki] = *(const f16x8*)(wl + 9216 + (kg * 64 + mt * 16 + ln) * 4);
    }
    const float4 pb4 = *(const float4*)(pre_b + i * 64 + mt * 16 + 4 * h4);
    const float4 fb = *(const float4*)(filt_b + i * 64 + mt * 16 + 4 * h4);
    const float4 gb = *(const float4*)(gate_b + i * 64 + mt * 16 + 4 * h4);
    const float4 pb = *(const float4*)(post_b + i * 64 + mt * 16 + 4 * h4);

#pragma unroll
    for (int sub = 0; sub < 2; ++sub) {
        const int bt = btp * 2 + sub;
        const int b = bt >> 3;
        const int tile = bt & 7;
        const int t0 = TFULL - DEC + tile * 32;
        const unsigned* xw = wsu + WTOT_U32 + b * 8192;

        // ---- P1: h[o-tile mt][cw] = relu(pre . x); nct MFMAs ----
        {
#pragma unroll
            for (int ct2 = 0; ct2 < 4; ++ct2) {
                if (ct2 >= nct) break;     // uniform branch (dil per block)
                const int cw = ct2 * 16 + ln;  // window col
                int ta = (dil >= 32) ? ((cw < 32) ? (t0 - dil + cw) : (t0 + cw - 32))
                                     : (t0 - dil + cw);
                const int tw = (ta - WIN0) & 511;   // wrap unused tail cols
                f16x8 bx = *(const f16x8*)(xw + tw * 16 + h4 * 4);
                f32x4 c = {0.f, 0.f, 0.f, 0.f};
                c = __builtin_amdgcn_mfma_f32_16x16x32_f16(aPre, bx, c, 0, 0, 0);
                uint2 hv;
                hv.x = pkrtz(fmaxf(c[0] + pb4.x, 0.f), fmaxf(c[1] + pb4.y, 0.f));
                hv.y = pkrtz(fmaxf(c[2] + pb4.z, 0.f), fmaxf(c[3] + pb4.w, 0.f));
                *(uint2*)&lds[cw * HSTR + mt * 8 + h4 * 2] = hv;
            }
        }
        __syncthreads();

        // ---- P2: F,G for both col-halves; pure LDS+MFMA, 4 acc chains ----
        {
            f32x4 cf[2], cg[2];
#pragma unroll
            for (int nt = 0; nt < 2; ++nt) {
                cf[nt] = (f32x4){0.f, 0.f, 0.f, 0.f};
                cg[nt] = (f32x4){0.f, 0.f, 0.f, 0.f};
            }
#pragma unroll
            for (int m = 0; m < 4; ++m) {
#pragma unroll
                for (int nt = 0; nt < 2; ++nt) {
                    const int t = nt * 16 + ln;
                    const int row = (m >> 1) ? (t + off1) : t;   // tap select
                    uint4 bf4 = *(const uint4*)&lds[row * HSTR + 16 * (m & 1) + 4 * h4];
                    f16x8 bfrag = __builtin_bit_cast(f16x8, bf4);
                    cf[nt] = __builtin_amdgcn_mfma_f32_16x16x32_f16(af[m], bfrag, cf[nt], 0, 0, 0);
                    cg[nt] = __builtin_amdgcn_mfma_f32_16x16x32_f16(ag[m], bfrag, cg[nt], 0, 0, 0);
                }
            }
#pragma unroll
            for (int nt = 0; nt < 2; ++nt) {
                const int t = nt * 16 + ln;
                float s0 = fast_tanh(cf[nt][0] + fb.x) * fmaxf(cg[nt][0] + gb.x, 0.f);
                float s1 = fast_tanh(cf[nt][1] + fb.y) * fmaxf(cg[nt][1] + gb.y, 0.f);
                float s2 = fast_tanh(cf[nt][2] + fb.z) * fmaxf(cg[nt][2] + gb.z, 0.f);
                float s3 = fast_tanh(cf[nt][3] + fb.w) * fmaxf(cg[nt][3] + gb.w, 0.f);
                uint2 sv;
                sv.x = pkrtz(s0, s1);
                sv.y = pkrtz(s2, s3);
                *(uint2*)&lds[HU + t * SSTR + mt * 8 + h4 * 2] = sv;
            }
        }
        __syncthreads();

        // ---- P3: P (K=64) for both col-halves; coalesced uint2 write ----
        {
            unsigned* po = pout + (size_t)(i * 256 + bt) * 1024;
#pragma unroll
            for (int nt = 0; nt < 2; ++nt) {
                const int t = nt * 16 + ln;
                f32x4 cp = {0.f, 0.f, 0.f, 0.f};
#pragma unroll
                for (int ki = 0; ki < 2; ++ki) {
                    const int kg = 4 * ki + h4;      // c0 = 8*kg
                    f16x8 bs = *(const f16x8*)&lds[HU + t * SSTR + 4 * kg];
                    cp = __builtin_amdgcn_mfma_f32_16x16x32_f16(ap[ki], bs, cp, 0, 0, 0);
                }
                // partial layout: [q16][t32][2] u32, q = o>>2 = mt*4+h4
                uint2 o2;
                o2.x = pkrtz(fmaxf(cp[0] + pb.x, 0.f), fmaxf(cp[1] + pb.y, 0.f));
                o2.y = pkrtz(fmaxf(cp[2] + pb.z, 0.f), fmaxf(cp[3] + pb.w, 0.f));
                *(uint2*)&po[(mt * 4 + h4) * 64 + 2 * t] = o2;
            }
        }
    }
}

// ---------------- head: skip-sum + dense 64 -> 128 -> 1, 16 cols/block ------
// grid 512 = bt(256) x half(2); 512 threads; 2 blocks/CU.
__global__ __launch_bounds__(512) void wavenet_head16(
    const unsigned* __restrict__ pin,
    const float* __restrict__ d1_w, const float* __restrict__ d1_b,
    const float* __restrict__ d2_w, const float* __restrict__ d2_b,
    float* __restrict__ out)
{
    __shared__ __align__(16) float accf[64 * 20];   // [c64][tc16] stride 20
    __shared__ __align__(16) float zbuf[128 * 16];  // [p128][tc16]
    __shared__ float red[16 * 8];
    const int tid = threadIdx.x;
    const int bt = blockIdx.x >> 1;
    const int half = blockIdx.x & 1;

    // ---- A: skip-sum (8 layers) for 16 cols; o = 4q+oo ----
    if (tid < 256) {
        const int q = tid >> 4, tc = tid & 15;
        const int t = half * 16 + tc;
        float a0 = 0.f, a1 = 0.f, a2 = 0.f, a3 = 0.f;
#pragma unroll
        for (int l = 0; l < 8; ++l) {
            const unsigned* p = pin + (size_t)(l * 256 + bt) * 1024;
            uint2 u = *(const uint2*)&p[q * 64 + 2 * t];
            half2_t u0 = h2(u.x), u1 = h2(u.y);
            a0 += (float)u0[0]; a1 += (float)u0[1];
            a2 += (float)u1[0]; a3 += (float)u1[1];
        }
        accf[(4 * q + 0) * 20 + tc] = a0;
        accf[(4 * q + 1) * 20 + tc] = a1;
        accf[(4 * q + 2) * 20 + tc] = a2;
        accf[(4 * q + 3) * 20 + tc] = a3;
    }
    __syncthreads();

    // ---- B: d1 (128x64) x acc, 4 cols/thread (256 fma) + relu + d2 scale ----
    {
        const int p = tid >> 2, tc0 = (tid & 3) * 4;
        float z0 = d1_b[p], z1 = z0, z2 = z0, z3 = z0;
        const float4* w4 = (const float4*)(d1_w + p * 64);
#pragma unroll 4
        for (int c4 = 0; c4 < 16; ++c4) {
            float4 w = w4[c4];
#pragma unroll
            for (int cc = 0; cc < 4; ++cc) {
                const float wv = (cc == 0) ? w.x : (cc == 1) ? w.y : (cc == 2) ? w.z : w.w;
                float4 av = *(const float4*)&accf[(c4 * 4 + cc) * 20 + tc0];
                z0 = fmaf(wv, av.x, z0);
                z1 = fmaf(wv, av.y, z1);
                z2 = fmaf(wv, av.z, z2);
                z3 = fmaf(wv, av.w, z3);
            }
        }
        const float dw = d2_w[p];
        float4 zo;
        zo.x = fmaxf(z0, 0.f) * dw;
        zo.y = fmaxf(z1, 0.f) * dw;
        zo.z = fmaxf(z2, 0.f) * dw;
        zo.w = fmaxf(z3, 0.f) * dw;
        *(float4*)&zbuf[p * 16 + tc0] = zo;
    }
    __syncthreads();

    // ---- C: reduce 128 p per col ----
    if (tid < 128) {
        const int tc = tid >> 3, seg = tid & 7;
        float sum = 0.f;
#pragma unroll
        for (int k = 0; k < 16; ++k)
            sum += zbuf[(seg * 16 + k) * 16 + tc];
        red[tc * 8 + seg] = sum;
    }
    __syncthreads();
    if (tid < 16) {
        float sum = d2_b[0];
#pragma unroll
        for (int g = 0; g < 8; ++g) sum += red[tid * 8 + g];
        out[bt * 32 + half * 16 + tid] = fmaxf(sum, 0.f);
    }
}

// ================= fallback: fp32 fused (no ws) =================
#define HROW 164
#define SROW 33
__global__ __launch_bounds__(512) void wavenet_main(
    const float* __restrict__ x,
    const float* __restrict__ pre_w, const float* __restrict__ pre_b,
    const float* __restrict__ filt_w, const float* __restrict__ filt_b,
    const float* __restrict__ gate_w, const float* __restrict__ gate_b,
    const float* __restrict__ post_w, const float* __restrict__ post_b,
    const float* __restrict__ d1_w, const float* __restrict__ d1_b,
    const float* __restrict__ d2_w, const float* __restrict__ d2_b,
    float* __restrict__ out)
{
    __shared__ __align__(16) float h_s[64 * HROW];
    __shared__ __align__(16) float wbuf[20480];
    __shared__ __align__(16) float s_s[64 * SROW];
    const int tid = threadIdx.x;
    const int b = blockIdx.x >> 3;
    const int tile = blockIdx.x & 7;
    const int t0 = TFULL - DEC + tile * 32;
    const int lane = tid & 63;
    const int wv = __builtin_amdgcn_readfirstlane(tid >> 6);
    const int q = tid >> 5;
    const int tt = tid & 31;
    float accp[4] = {0.f, 0.f, 0.f, 0.f};
    for (int i = 0; i < 8; ++i) {
        const int dil = 1 << i;
        const int NC = 32 + dil;
        for (int m = tid; m < 8192; m += 512) {
            int c = m >> 7, rem = m & 127, o = rem >> 1, k = m & 1;
            wbuf[m] = filt_w[((i * 64 + o) * 64 + c) * 2 + k];
            wbuf[8192 + m] = gate_w[((i * 64 + o) * 64 + c) * 2 + k];
        }
        for (int m = tid; m < 4096; m += 512) {
            int c = m >> 6, o = m & 63;
            wbuf[16384 + m] = post_w[(i * 64 + o) * 64 + c];
        }
        __syncthreads();
        {
            const float* preb = pre_b + i * 64 + wv * 8;
            const float* prew = pre_w + (i * 64 + wv * 8) * 32;
            for (int col = lane; col < NC; col += 64) {
                int ta = t0 - dil + col;
                const float* xp = x + (size_t)b * 32 * TFULL + ta;
                float hacc[8];
#pragma unroll
                for (int r = 0; r < 8; ++r) hacc[r] = preb[r];
                for (int ci = 0; ci < 32; ++ci) {
                    float xv = xp[ci * TFULL];
#pragma unroll
                    for (int r = 0; r < 8; ++r)
                        hacc[r] = fmaf(prew[r * 32 + ci], xv, hacc[r]);
                }
#pragma unroll
                for (int r = 0; r < 8; ++r)
                    h_s[(wv * 8 + r) * HROW + col] = fmaxf(hacc[r], 0.f);
            }
        }
        __syncthreads();
        {
            float fa[4], ga[4];
#pragma unroll
            for (int oo = 0; oo < 4; ++oo) {
                fa[oo] = filt_b[i * 64 + q * 4 + oo];
                ga[oo] = gate_b[i * 64 + q * 4 + oo];
            }
            const float4* fw4 = (const float4*)wbuf;
            const float4* gw4 = (const float4*)(wbuf + 8192);
            const float* hrow0 = h_s + tt;
            const float* hrow1 = h_s + tt + dil;
#pragma unroll 4
            for (int c = 0; c < 64; ++c) {
                float4 f0 = fw4[c * 32 + q * 2];
                float4 f1 = fw4[c * 32 + q * 2 + 1];
                float4 g0 = gw4[c * 32 + q * 2];
                float4 g1 = gw4[c * 32 + q * 2 + 1];
                float h0 = hrow0[c * HROW];
                float h1 = hrow1[c * HROW];
                fa[0] = fmaf(f0.x, h0, fmaf(f0.y, h1, fa[0]));
                fa[1] = fmaf(f0.z, h0, fmaf(f0.w, h1, fa[1]));
                fa[2] = fmaf(f1.x, h0, fmaf(f1.y, h1, fa[2]));
                fa[3] = fmaf(f1.z, h0, fmaf(f1.w, h1, fa[3]));
                ga[0] = fmaf(g0.x, h0, fmaf(g0.y, h1, ga[0]));
                ga[1] = fmaf(g0.z, h0, fmaf(g0.w, h1, ga[1]));
                ga[2] = fmaf(g1.x, h0, fmaf(g1.y, h1, ga[2]));
                ga[3] = fmaf(g1.z, h0, fmaf(g1.w, h1, ga[3]));
            }
#pragma unroll
            for (int oo = 0; oo < 4; ++oo)
                s_s[(q * 4 + oo) * SROW + tt] = fast_tanh(fa[oo]) * fmaxf(ga[oo], 0.f);
        }
        __syncthreads();
        {
            float pa[4];
#pragma unroll
            for (int oo = 0; oo < 4; ++oo) pa[oo] = post_b[i * 64 + q * 4 + oo];
            const float4* pw4 = (const float4*)(wbuf + 16384);
#pragma unroll 4
            for (int c = 0; c < 64; ++c) {
                float4 pv = pw4[c * 16 + q];
                float sv = s_s[c * SROW + tt];
                pa[0] = fmaf(pv.x, sv, pa[0]);
                pa[1] = fmaf(pv.y, sv, pa[1]);
                pa[2] = fmaf(pv.z, sv, pa[2]);
                pa[3] = fmaf(pv.w, sv, pa[3]);
            }
#pragma unroll
            for (int oo = 0; oo < 4; ++oo) accp[oo] += fmaxf(pa[oo], 0.f);
        }
        __syncthreads();
    }
#pragma unroll
    for (int oo = 0; oo < 4; ++oo) s_s[(q * 4 + oo) * SROW + tt] = accp[oo];
    __syncthreads();
    {
        const int pg = tid >> 5;
        float partial = 0.f;
#pragma unroll
        for (int pp = 0; pp < 8; ++pp) {
            const int p = pg * 8 + pp;
            float z = d1_b[p];
            const float4* w4 = (const float4*)(d1_w + p * 64);
#pragma unroll 4
            for (int c4 = 0; c4 < 16; ++c4) {
                float4 w = w4[c4];
                z = fmaf(w.x, s_s[(c4 * 4 + 0) * SROW + tt], z);
                z = fmaf(w.y, s_s[(c4 * 4 + 1) * SROW + tt], z);
                z = fmaf(w.z, s_s[(c4 * 4 + 2) * SROW + tt], z);
                z = fmaf(w.w, s_s[(c4 * 4 + 3) * SROW + tt], z);
            }
            partial = fmaf(d2_w[p], fmaxf(z, 0.f), partial);
        }
        h_s[pg * 32 + tt] = partial;
    }
    __syncthreads();
    if (tid < 32) {
        float sum = d2_b[0];
#pragma unroll
        for (int g = 0; g < 16; ++g) sum += h_s[g * 32 + tid];
        out[b * DEC + tile * 32 + tid] = fmaxf(sum, 0.f);
    }
}

extern "C" void kernel_launch(void* const* d_in, const int* in_sizes, int n_in,
                              void* d_out, int out_size, void* d_ws, size_t ws_size,
                              hipStream_t stream)
{
    const float* x      = (const float*)d_in[0];
    const float* pre_w  = (const float*)d_in[1];
    const float* pre_b  = (const float*)d_in[2];
    const float* filt_w = (const float*)d_in[3];
    const float* filt_b = (const float*)d_in[4];
    const float* gate_w = (const float*)d_in[5];
    const float* gate_b = (const float*)d_in[6];
    const float* post_w = (const float*)d_in[7];
    const float* post_b = (const float*)d_in[8];
    const float* d1_w   = (const float*)d_in[9];
    const float* d1_b   = (const float*)d_in[10];
    const float* d2_w   = (const float*)d_in[11];
    const float* d2_b   = (const float*)d_in[12];
    float* out = (float*)d_out;

    if (ws_size >= WS_NEED2) {
        unsigned* ws = (unsigned*)d_ws;
        unsigned* part = ws + XP_U32;
        wavenet_prep16<<<688, 512, 0, stream>>>(x, pre_w, filt_w, gate_w, post_w, ws);
        wavenet_mfma4<<<1024, 256, 0, stream>>>(
            ws, pre_b, filt_b, gate_b, post_b, part);
        wavenet_head16<<<512, 512, 0, stream>>>(
            part, d1_w, d1_b, d2_w, d2_b, out);
    } else {
        wavenet_main<<<256, 512, 0, stream>>>(
            x, pre_w, pre_b, filt_w, filt_b, gate_w, gate_b, post_w, post_b,
            d1_w, d1_b, d2_w, d2_b, out);
    }
}